// Round 1
// baseline (79.485 us; speedup 1.0000x reference)
//
#include <hip/hip_runtime.h>
#include <hip/hip_bf16.h>

#define NV 8192
#define NF 16384
#define BATCH 32
#define WORDS 256   // 8192 bits / 32 per row

// ---------------------------------------------------------------------------
// Kernel 1: scatter face edges into the bit-adjacency matrix.
// L.at[rows,cols].set(-1) semantics == bitmask OR (duplicates collapse).
// Both directions of each of the 3 face edges, matching the reference.
// ---------------------------------------------------------------------------
__global__ void scatter_faces(const int* __restrict__ faces,
                              unsigned* __restrict__ adj, int nf) {
    int f = blockIdx.x * blockDim.x + threadIdx.x;
    if (f >= nf) return;
    int a = faces[f * 3 + 0];
    int b = faces[f * 3 + 1];
    int c = faces[f * 3 + 2];
    // set (r,c) bit
    #define SETBIT(r, cc) atomicOr(&adj[(r) * WORDS + ((cc) >> 5)], 1u << ((cc) & 31))
    SETBIT(a, b); SETBIT(b, a);
    SETBIT(b, c); SETBIT(c, b);
    SETBIT(c, a); SETBIT(a, c);
    #undef SETBIT
}

// ---------------------------------------------------------------------------
// Kernel 2: one block per vertex v.
//   deg(v) = popcount(row)   (includes self-bit if a degenerate face set it)
//   y[b,v,d] = x[b,v,d] - (1/deg) * sum_{w in N(v), w != v} x[b,w,d]   (deg>0)
//   partials[b*NV + v] = sum_d y^2
// 96 active threads: t -> (b = t/3, d = t%3).
// ---------------------------------------------------------------------------
__global__ __launch_bounds__(128)
void vertex_kernel(const float* __restrict__ x,
                   const unsigned* __restrict__ adj,
                   float* __restrict__ partials) {
    const int v = blockIdx.x;
    const int t = threadIdx.x;

    __shared__ unsigned row[WORDS];
    __shared__ float lsq[96];
    __shared__ int degsh;

    // stage bit-row into LDS (256 words, 128 threads -> 2 each)
    for (int i = t; i < WORDS; i += 128) row[i] = adj[v * WORDS + i];
    if (t == 0) degsh = 0;
    __syncthreads();

    // degree = popcount of the row
    int pc = 0;
    for (int i = t; i < WORDS; i += 128) pc += __popc(row[i]);
    for (int off = 32; off > 0; off >>= 1) pc += __shfl_down(pc, off);
    if ((t & 63) == 0) atomicAdd(&degsh, pc);
    __syncthreads();
    const int deg = degsh;

    const bool active = (t < 96);
    const int b = t / 3;
    const int d = t - 3 * b;

    float sum = 0.0f;
    // scan bit-row; loop is wave-uniform (row[] broadcast from LDS)
    for (int i = 0; i < WORDS; ++i) {
        unsigned wbits = row[i];
        while (wbits) {
            int bit = __ffs(wbits) - 1;
            wbits &= (wbits - 1);
            int w = (i << 5) + bit;
            if (active && w != v) {
                sum += x[(b * NV + w) * 3 + d];
            }
        }
    }

    float y = 0.0f;
    if (active && deg > 0) {
        y = x[(b * NV + v) * 3 + d] - sum / (float)deg;
    }
    if (active) lsq[t] = y * y;
    __syncthreads();

    if (t < BATCH) {
        float s = lsq[3 * t] + lsq[3 * t + 1] + lsq[3 * t + 2];
        partials[t * NV + v] = s;   // [b][v] layout for coalesced reduce
    }
}

// ---------------------------------------------------------------------------
// Kernel 3: deterministic per-batch reduction: out[b] = sum_v partials[b][v]/NV
// ---------------------------------------------------------------------------
__global__ __launch_bounds__(256)
void reduce_kernel(const float* __restrict__ partials,
                   float* __restrict__ out) {
    const int b = blockIdx.x;       // 32 blocks
    const int t = threadIdx.x;      // 256 threads
    float s = 0.0f;
    for (int i = t; i < NV; i += 256) s += partials[b * NV + i];
    for (int off = 32; off > 0; off >>= 1) s += __shfl_down(s, off);
    __shared__ float sh[4];
    if ((t & 63) == 0) sh[t >> 6] = s;
    __syncthreads();
    if (t == 0) out[b] = (sh[0] + sh[1] + sh[2] + sh[3]) / (float)NV;
}

extern "C" void kernel_launch(void* const* d_in, const int* in_sizes, int n_in,
                              void* d_out, int out_size, void* d_ws, size_t ws_size,
                              hipStream_t stream) {
    const float* x    = (const float*)d_in[0];   // (32, 8192, 3) f32
    const int* faces  = (const int*)d_in[1];     // (16384, 3) i32
    float* out        = (float*)d_out;           // (32,) f32

    unsigned* adj   = (unsigned*)d_ws;                         // 8 MiB
    float* partials = (float*)((char*)d_ws + (size_t)NV * WORDS * 4); // 1 MiB

    // zero adjacency every call (ws is poisoned once, never re-poisoned)
    hipMemsetAsync(adj, 0, (size_t)NV * WORDS * sizeof(unsigned), stream);

    scatter_faces<<<(NF + 255) / 256, 256, 0, stream>>>(faces, adj, NF);
    vertex_kernel<<<NV, 128, 0, stream>>>(x, adj, partials);
    reduce_kernel<<<BATCH, 256, 0, stream>>>(partials, out);
}

// Round 2
// 30.835 us; speedup vs baseline: 2.5778x; 2.5778x over previous
//
#include <hip/hip_runtime.h>
#include <hip/hip_bf16.h>

#define NV 8192
#define NF 16384
#define BATCH 32
#define WORDS 256   // 8192 bits / 32 per row
#define MAXD 64     // neighbor-list capacity (Poisson(12) max ~30 on this dataset)

// ---------------------------------------------------------------------------
// Kernel 1: scatter face edges into the bit-adjacency matrix.
// .set(-1) semantics == bitmask OR (duplicates collapse).
// ---------------------------------------------------------------------------
__global__ void scatter_faces(const int* __restrict__ faces,
                              unsigned* __restrict__ adj, int nf) {
    int f = blockIdx.x * blockDim.x + threadIdx.x;
    if (f >= nf) return;
    int a = faces[f * 3 + 0];
    int b = faces[f * 3 + 1];
    int c = faces[f * 3 + 2];
    #define SETBIT(r, cc) atomicOr(&adj[(r) * WORDS + ((cc) >> 5)], 1u << ((cc) & 31))
    SETBIT(a, b); SETBIT(b, a);
    SETBIT(b, c); SETBIT(c, b);
    SETBIT(c, a); SETBIT(a, c);
    #undef SETBIT
}

// ---------------------------------------------------------------------------
// Kernel 2: compact bit rows -> transposed neighbor lists.
// One wave (64 lanes) per vertex; lane l reads words [4l, 4l+4) as uint4.
//   deg[v] = full popcount (incl. self-bit)  -> the row-normalization divisor
//   cnt[v] = list length (self excluded)
//   nbr[k*NV + v] = k-th neighbor of v (order irrelevant; sum is commutative)
// ---------------------------------------------------------------------------
__global__ __launch_bounds__(256)
void compact_kernel(const unsigned* __restrict__ adj,
                    int* __restrict__ deg, int* __restrict__ cnt,
                    int* __restrict__ nbr) {
    const int v    = blockIdx.x * 4 + (threadIdx.x >> 6);
    const int lane = threadIdx.x & 63;

    const uint4 wq = *reinterpret_cast<const uint4*>(adj + (size_t)v * WORDS + lane * 4);
    unsigned wm[4] = {wq.x, wq.y, wq.z, wq.w};

    int pc = __popc(wm[0]) + __popc(wm[1]) + __popc(wm[2]) + __popc(wm[3]);

    // remove the self-bit from the list (but keep it in deg)
    const int selfword = v >> 5;
    const int base     = lane * 4;
    int c = pc;
    if (selfword >= base && selfword < base + 4) {
        unsigned m = 1u << (v & 31);
        if (wm[selfword - base] & m) { wm[selfword - base] &= ~m; c -= 1; }
    }

    // wave-wide totals + exclusive scan of c
    int incl = c;
    #pragma unroll
    for (int off = 1; off < 64; off <<= 1) {
        int o = __shfl_up(incl, off);
        if (lane >= off) incl += o;
    }
    const int ofs     = incl - c;
    const int total_c = __shfl(incl, 63);

    int pct = pc;
    #pragma unroll
    for (int off = 1; off < 64; off <<= 1) pct += __shfl_xor(pct, off);

    int idx = ofs;
    #pragma unroll
    for (int j = 0; j < 4; ++j) {
        unsigned bits = wm[j];
        const int wbase = (base + j) << 5;
        while (bits) {
            int bpos = __ffs(bits) - 1;
            bits &= bits - 1;
            if (idx < MAXD) nbr[idx * NV + v] = wbase + bpos;
            ++idx;
        }
    }
    if (lane == 0) {
        deg[v] = pct;
        cnt[v] = total_c < MAXD ? total_c : MAXD;
    }
}

// ---------------------------------------------------------------------------
// Kernel 3: gather. Grid = 32 batches x 8 vertex-groups, 1024 thr/block.
// Stage the whole batch slice x[b] (96 KB) in LDS, then each thread owns one
// vertex: sum neighbors from LDS, y = x[v] - sum/deg, r = |y|^2, block-reduce.
// ---------------------------------------------------------------------------
__global__ __launch_bounds__(1024)
void gather_kernel(const float* __restrict__ x,
                   const int* __restrict__ deg, const int* __restrict__ cnt,
                   const int* __restrict__ nbr,
                   float* __restrict__ partials) {
    __shared__ float lx[NV * 3];     // 96 KiB (gfx950: 160 KiB LDS/CU)
    __shared__ float red[16];

    const int t = threadIdx.x;
    const int b = blockIdx.x >> 3;
    const int g = blockIdx.x & 7;

    // stage x[b] : 24576 floats = 6144 float4, coalesced
    const float4* xs = reinterpret_cast<const float4*>(x + (size_t)b * NV * 3);
    float4* ls = reinterpret_cast<float4*>(lx);
    #pragma unroll
    for (int i = 0; i < 6; ++i) ls[t + i * 1024] = xs[t + i * 1024];
    __syncthreads();

    const int v  = g * 1024 + t;
    const int cv = cnt[v];
    const int dv = deg[v];

    float s0 = 0.f, s1 = 0.f, s2 = 0.f;
    for (int k = 0; k < cv; ++k) {
        const int w = nbr[k * NV + v] * 3;
        s0 += lx[w];
        s1 += lx[w + 1];
        s2 += lx[w + 2];
    }

    float r = 0.f;
    if (dv > 0) {
        const float inv = 1.0f / (float)dv;
        const float y0 = lx[v * 3]     - s0 * inv;
        const float y1 = lx[v * 3 + 1] - s1 * inv;
        const float y2 = lx[v * 3 + 2] - s2 * inv;
        r = y0 * y0 + y1 * y1 + y2 * y2;
    }

    // deterministic block reduction of r over 1024 threads
    #pragma unroll
    for (int off = 32; off > 0; off >>= 1) r += __shfl_down(r, off);
    if ((t & 63) == 0) red[t >> 6] = r;
    __syncthreads();
    if (t == 0) {
        float s = 0.f;
        #pragma unroll
        for (int i = 0; i < 16; ++i) s += red[i];
        partials[blockIdx.x] = s;
    }
}

// ---------------------------------------------------------------------------
// Kernel 4: out[b] = (sum of 8 group partials) / NV  — deterministic, tiny.
// ---------------------------------------------------------------------------
__global__ __launch_bounds__(64)
void final_reduce(const float* __restrict__ partials, float* __restrict__ out) {
    const int t = threadIdx.x;
    if (t < BATCH) {
        float s = 0.f;
        #pragma unroll
        for (int g = 0; g < 8; ++g) s += partials[t * 8 + g];
        out[t] = s / (float)NV;
    }
}

extern "C" void kernel_launch(void* const* d_in, const int* in_sizes, int n_in,
                              void* d_out, int out_size, void* d_ws, size_t ws_size,
                              hipStream_t stream) {
    const float* x   = (const float*)d_in[0];   // (32, 8192, 3) f32
    const int* faces = (const int*)d_in[1];     // (16384, 3) i32
    float* out       = (float*)d_out;           // (32,) f32

    char* ws = (char*)d_ws;
    unsigned* adj   = (unsigned*)ws;                                  // 8 MiB
    int* nbr        = (int*)(ws + (size_t)NV * WORDS * 4);            // 2 MiB
    int* deg        = (int*)(ws + (size_t)NV * WORDS * 4 + (size_t)MAXD * NV * 4);
    int* cnt        = deg + NV;
    float* partials = (float*)(cnt + NV);                             // 256 floats

    hipMemsetAsync(adj, 0, (size_t)NV * WORDS * sizeof(unsigned), stream);

    scatter_faces<<<(NF + 255) / 256, 256, 0, stream>>>(faces, adj, NF);
    compact_kernel<<<NV / 4, 256, 0, stream>>>(adj, deg, cnt, nbr);
    gather_kernel<<<BATCH * 8, 1024, 0, stream>>>(x, deg, cnt, nbr, partials);
    final_reduce<<<1, 64, 0, stream>>>(partials, out);
}